// Round 7
// baseline (327.064 us; speedup 1.0000x reference)
//
#include <hip/hip_runtime.h>
#include <hip/hip_bf16.h>

typedef unsigned int u32;
typedef unsigned short u16;
typedef unsigned long long u64;
typedef __bf16 bf16x8 __attribute__((ext_vector_type(8)));
typedef short short8 __attribute__((ext_vector_type(8)));
typedef float floatx4 __attribute__((ext_vector_type(4)));

__device__ inline float b2f(u16 b) { return __uint_as_float((u32)b << 16); }
__device__ inline float lo2f(u32 p) { return __uint_as_float(p << 16); }
__device__ inline float hi2f(u32 p) { return __uint_as_float(p & 0xffff0000u); }
__device__ inline u16 f2bs(float f) {   // RNE f32 -> bf16 bits
    __hip_bfloat16 h = __float2bfloat16(f);
    return *reinterpret_cast<u16*>(&h);
}
// element i of an external float array: f32 (fl=1) or packed bf16 (fl=0)
__device__ inline float ldext(const void* p, int fl, int i) {
    return fl ? ((const float*)p)[i] : b2f(((const u16*)p)[i]);
}

// ---------------------------------------------------------------------------
// flags[0]: edge stride (1 = int64 layout, 0 = int32)
// flags[1]: float inputs are f32 (1) or packed bf16 (0)
// flags[2]: E (edges per timestep), decided by probing data extent
// Also clears bkcnt[512] (folded memset: saves one dispatch).
__global__ __launch_bounds__(64) void detect_kernel(const int* __restrict__ eb,
                                                    const u32* __restrict__ xw,
                                                    int* __restrict__ flags,
                                                    int* __restrict__ bkcnt,
                                                    int S, int n) {
    __shared__ int sh[64 * 3];
    int lane = threadIdx.x & 63;
    for (int j = lane; j < 512; j += 64) bkcnt[j] = 0;
    int zc = 0, explo = 0;
#pragma unroll
    for (int r = 0; r < 4; ++r) {
        int i = 64 * r + lane;
        zc += (eb[2 * i + 1] == 0) ? 1 : 0;   // int64: odd dwords are hi-words = 0
        u32 w = xw[i];
        int e = (int)((w >> 7) & 0xFF);       // exponent field of LOW half as bf16
        explo += (e >= 96 && e <= 140) ? 1 : 0;
    }
    sh[lane] = zc;
    sh[64 + lane] = explo;
    __syncthreads();
    int fl = 0;
    {
        int z = 0;
        for (int j = 0; j < 64; ++j) z += sh[j];
        fl = (z > 200) ? 1 : 0;   // wave-uniform
    }
    // probe logical indices [S/2, S/2+256): valid node ids => S counts logical
    // elements (E = S/4); garbage => S counts int32 words (E = S/8).
    int vc = 0;
#pragma unroll
    for (int r = 0; r < 4; ++r) {
        int li = S / 2 + 64 * r + lane;
        int v = fl ? eb[2 * li] : eb[li];
        vc += ((unsigned)v < (unsigned)n) ? 1 : 0;
    }
    sh[128 + lane] = vc;
    __syncthreads();
    if (lane == 0) {
        int vtot = 0, etot = 0;
        for (int j = 0; j < 64; ++j) vtot += sh[128 + j];
        for (int j = 0; j < 64; ++j) etot += sh[64 + j];
        flags[0] = fl;
        flags[1] = (etot >= 192) ? 0 : 1;   // bf16-packed signature else f32
        flags[2] = (vtot >= 240) ? (S / 4) : (S / 8);
    }
}

__device__ inline int load_edge(const int* eb, int fl, int idx) {
    return eb[fl ? (idx << 1) : idx];
}

// ---------------------------------------------------------------------------
// CSR build pass 1 (both timesteps): partition edges into global-dst-range
// buckets at FIXED capacity capP (region b*capP, no scan needed). Per-block
// LDS histogram -> one global atomicAdd per bucket -> (g_dst, g_src) u64
// pairs in ~150 B contiguous runs (near-full cache lines). Src stored as
// GLOBAL id t*N+src. Blocks >= gP instead transpose W1,W2 -> bf16 W1t,W2t
// (folded prep_w: saves one dispatch).
#define PCHUNK 4096
__global__ __launch_bounds__(256) void part_kernel(const int* __restrict__ eb,
                                                   const int* __restrict__ flags,
                                                   int* __restrict__ bkcnt,
                                                   u64* __restrict__ pairs,
                                                   int n, int shift, int capP,
                                                   int gP,
                                                   const void* __restrict__ W1,
                                                   const void* __restrict__ W2,
                                                   u16* __restrict__ W1t,
                                                   u16* __restrict__ W2t) {
    __shared__ int cnt[512];
    __shared__ int gbase[512];
    if ((int)blockIdx.x >= gP) {             // prep_w tail blocks
        int tid = (blockIdx.x - gP) * 256 + threadIdx.x;
        if (tid < 2 * 128 * 128) {
            int which = tid >> 14;
            int r = tid & 16383;
            const void* W = which ? W2 : W1;
            u16* Wt = which ? W2t : W1t;
            int c = r >> 7, k = r & 127;
            Wt[c * 128 + k] = f2bs(ldext(W, flags[1], k * 128 + c));
        }
        return;
    }
    const int E = flags[2];
    const int fl = flags[0];
    const int nbuk = (2 * n + (1 << shift) - 1) >> shift;
    const int tid = threadIdx.x;
    for (int i = tid; i < nbuk; i += 256) cnt[i] = 0;
    __syncthreads();
    const int e0 = blockIdx.x * PCHUNK;
    u32 sv[16]; int gv[16], rk[16];
#pragma unroll
    for (int j = 0; j < 16; ++j) {
        int e = e0 + j * 256 + tid;
        u32 gs = 0; int g = -1;
        if (e < 2 * E) {
            int t = (e >= E) ? 1 : 0;
            int le = e - t * E;
            gs = (u32)(t * n) + (u32)load_edge(eb, fl, t * 2 * E + le);
            unsigned du = (unsigned)load_edge(eb, fl, t * 2 * E + E + le);
            if (du < (unsigned)n) g = t * n + (int)du;
        }
        sv[j] = gs;
        gv[j] = g;
        rk[j] = (g >= 0) ? atomicAdd(&cnt[g >> shift], 1) : 0;   // rank in bucket
    }
    __syncthreads();
    for (int b = tid; b < nbuk; b += 256) {
        int c = cnt[b];
        gbase[b] = c ? atomicAdd(&bkcnt[b], c) : 0;              // reserve run
    }
    __syncthreads();
#pragma unroll
    for (int j = 0; j < 16; ++j) {
        if (gv[j] >= 0) {
            int b = gv[j] >> shift;
            int idx = gbase[b] + rk[j];
            if (idx < capP)                                      // overflow guard
                pairs[(size_t)b * capP + idx] =
                    ((u64)(u32)gv[j] << 32) | sv[j];
        }
    }
}

// ---------------------------------------------------------------------------
// CSR build pass 2: one block per bucket. LDS histogram of the bucket's pairs
// gives local degrees; LDS exclusive scan over 4-ALIGNED (padded) degrees
// gives each node a 4-aligned start in the sparse ssrc layout (enables int4
// edge-index loads in the gather; pad slots are never consumed because the
// gather clamps e>=end elements to the zero row). deg/off/dinv coalesced;
// then in-bucket ssrc scatter (~16 KB window, L2-hot, full-line writebacks).
__global__ __launch_bounds__(256) void scat_kernel(const u64* __restrict__ pairs,
                                                   const int* __restrict__ bkcnt,
                                                   int* __restrict__ deg,
                                                   int* __restrict__ off,
                                                   float* __restrict__ dinv,
                                                   int* __restrict__ ssrc,
                                                   int n2, int shift, int capP) {
    __shared__ int hist[1024];   // histogram, then reused as scatter cursors
    __shared__ int lscan[256];
    const int b = blockIdx.x;
    const int d0 = b << shift;
    if (d0 >= n2) return;
    int nn = (1 << shift);
    if (d0 + nn > n2) nn = n2 - d0;
    const int tid = threadIdx.x;
    for (int j = tid; j < nn; j += 256) hist[j] = 0;
    __syncthreads();
    int cnt = bkcnt[b];
    if (cnt > capP) cnt = capP;
    const int gb = b * capP;                 // fixed sparse base (4-aligned)
    const u64* pb = pairs + (size_t)gb;
    for (int i = tid; i < cnt; i += 256) {
        unsigned dl = (unsigned)(int)(pb[i] >> 32) - (unsigned)d0;
        if (dl < (unsigned)nn) atomicAdd(&hist[dl], 1);
    }
    __syncthreads();
    // exclusive scan of PADDED degrees: thread t owns elements [4t, 4t+4)
    int base4 = tid * 4;
    int s0 = 0, s1 = 0, s2 = 0, s3 = 0;
    if (base4 < nn) {
        s0 = hist[base4];
        s1 = (base4 + 1 < nn) ? hist[base4 + 1] : 0;
        s2 = (base4 + 2 < nn) ? hist[base4 + 2] : 0;
        s3 = (base4 + 3 < nn) ? hist[base4 + 3] : 0;
    }
    int p0 = (s0 + 3) & ~3, p1 = (s1 + 3) & ~3;
    int p2 = (s2 + 3) & ~3, p3 = (s3 + 3) & ~3;
    int tsum = p0 + p1 + p2 + p3;
    lscan[tid] = tsum;
    __syncthreads();
    int val = tsum;
    for (int o = 1; o < 256; o <<= 1) {
        int add = (tid >= o) ? lscan[tid - o] : 0;
        __syncthreads();
        val += add;
        lscan[tid] = val;
        __syncthreads();
    }
    int texcl = val - tsum;                  // exclusive prefix (padded)
    if (base4 < nn) {
        int g = d0 + base4;
        int o0 = gb + texcl;
        deg[g] = s0; off[g] = o0; dinv[g] = rsqrtf((float)(s0 + 1));
        hist[base4] = o0;
        if (base4 + 1 < nn) {
            int o1 = o0 + p0;
            deg[g + 1] = s1; off[g + 1] = o1; dinv[g + 1] = rsqrtf((float)(s1 + 1));
            hist[base4 + 1] = o1;
        }
        if (base4 + 2 < nn) {
            int o2 = o0 + p0 + p1;
            deg[g + 2] = s2; off[g + 2] = o2; dinv[g + 2] = rsqrtf((float)(s2 + 1));
            hist[base4 + 2] = o2;
        }
        if (base4 + 3 < nn) {
            int o3 = o0 + p0 + p1 + p2;
            deg[g + 3] = s3; off[g + 3] = o3; dinv[g + 3] = rsqrtf((float)(s3 + 1));
            hist[base4 + 3] = o3;
        }
    }
    __syncthreads();
    const int limit = gb + capP;
    for (int i = tid; i < cnt; i += 256) {
        u64 p = pb[i];
        unsigned dl = (unsigned)(int)(p >> 32) - (unsigned)d0;
        if (dl < (unsigned)nn) {
            int pos = atomicAdd(&hist[dl], 1);
            if (pos < limit) ssrc[pos] = (int)(u32)p;
        }
    }
}

// ---------------------------------------------------------------------------
// MFMA GEMM over the unified 2N-row space: hs[g][c] = bf16( dinv[g] * X[g].W )
// mfma_f32_16x16x32_bf16. Block = 4 waves, 64 rows/block; wave = 16 rows x
// 128 cols = 8 col-tiles x 4 K-steps = 32 MFMAs. Wt staged in LDS, row
// stride 136 bf16 (2-way bank aliasing only -> free). Block 0 also zeroes
// the gather pad row at index n (folded memset; runs after scat consumed
// the aliased pairs region, before any gather reads it).
// Verified layouts (learn_hip m89/m91): A[m=lane&15][k=quad*8+j],
// B[n=lane&15][k=quad*8+j], C/D col=lane&15, row=quad*4+reg.
__global__ __launch_bounds__(256) void gemm_mfma(const void* __restrict__ Xv,
                                                 int x_ext,
                                                 const u16* __restrict__ Wt,
                                                 const int* __restrict__ flags,
                                                 const float* __restrict__ dinv,
                                                 u16* __restrict__ hs, int n) {
    if (blockIdx.x == 0 && threadIdx.x < 64)
        ((u32*)hs)[(size_t)n * 64 + threadIdx.x] = 0;   // pad row
    __shared__ u16 Ws[128 * 136];  // Wt[c][k], padded stride 136
    {
        u32* wsu = (u32*)Ws;
        const u32* wtu = (const u32*)Wt;
        for (int i = threadIdx.x; i < 128 * 64; i += 256) {
            int c = i >> 6, kk = i & 63;
            wsu[c * 68 + kk] = wtu[i];
        }
    }
    __syncthreads();

    const int wave = threadIdx.x >> 6;
    const int lane = threadIdx.x & 63;
    const int m = lane & 15;
    const int quad = lane >> 4;
    const int node0 = blockIdx.x * 64 + wave * 16;
    if (node0 >= n) return;

    const int xf32 = x_ext ? flags[1] : 0;   // internal buffers are bf16
    int va = node0 + m;
    if (va > n - 1) va = n - 1;              // clamp; stores guarded

    floatx4 acc[8];
#pragma unroll
    for (int t = 0; t < 8; ++t) acc[t] = (floatx4){0.f, 0.f, 0.f, 0.f};

#pragma unroll
    for (int ks = 0; ks < 4; ++ks) {
        bf16x8 a;
        if (xf32) {
            const float* Xf = (const float*)Xv + (size_t)va * 128 + ks * 32 + quad * 8;
            float4 x0 = *(const float4*)Xf;
            float4 x1 = *(const float4*)(Xf + 4);
            short8 as;
            as[0] = (short)f2bs(x0.x); as[1] = (short)f2bs(x0.y);
            as[2] = (short)f2bs(x0.z); as[3] = (short)f2bs(x0.w);
            as[4] = (short)f2bs(x1.x); as[5] = (short)f2bs(x1.y);
            as[6] = (short)f2bs(x1.z); as[7] = (short)f2bs(x1.w);
            a = __builtin_bit_cast(bf16x8, as);
        } else {
            const u16* Xb = (const u16*)Xv + (size_t)va * 128 + ks * 32 + quad * 8;
            a = *(const bf16x8*)Xb;
        }
#pragma unroll
        for (int t = 0; t < 8; ++t) {
            const bf16x8 b = *(const bf16x8*)(Ws + (16 * t + m) * 136 + ks * 32 + quad * 8);
            acc[t] = __builtin_amdgcn_mfma_f32_16x16x32_bf16(a, b, acc[t], 0, 0, 0);
        }
    }

#pragma unroll
    for (int r = 0; r < 4; ++r) {
        int v = node0 + quad * 4 + r;
        if (v < n) {
            float dv = dinv[v];
#pragma unroll
            for (int t = 0; t < 8; ++t)
                hs[(size_t)v * 128 + 16 * t + m] = f2bs(acc[t][r] * dv);
        }
    }
}

// ---------------------------------------------------------------------------
// out[g] = act( dinv[g] * (hs[g] + sum_{u in in(g)} hs[u]) + bias ), g in [0,2N)
// PERSISTENT grid-stride waves (8192 waves = full residency): each wave
// handles ~n2/8192 nodes, smoothing Poisson-degree imbalance (was: one node
// per wave -> block waits on its slowest wave, ~71% occupancy). Next node's
// off/deg prefetched before processing the current node. Row loads keep the
// full-wave 256 B contiguous pattern (round-5 lesson: multi-row dwordx4
// address divergence is 2.7x slower). Edge indices via int4 (4-aligned CSR
// starts; clamp to zero pad row at n2). Lane owns column pair 2*lane.
// If imp != null, rows g >= half wave-reduce importance = final . Wc + bc.
__global__ __launch_bounds__(256) void gather_kernel(const u16* __restrict__ hs,
                                                     const int* __restrict__ off,
                                                     const int* __restrict__ deg,
                                                     const int* __restrict__ ssrc,
                                                     const float* __restrict__ dinv,
                                                     const void* __restrict__ bias,
                                                     const int* __restrict__ flags,
                                                     float* __restrict__ outf,
                                                     u16* __restrict__ outb,
                                                     const void* __restrict__ Wc,
                                                     const void* __restrict__ bc,
                                                     float* __restrict__ imp,
                                                     int n2, int half, int relu,
                                                     int nwaves) {
    const int lane = threadIdx.x & 63;
    int w = (blockIdx.x * 256 + threadIdx.x) >> 6;
    if (w >= n2) return;

    const u32* hsu = (const u32*)hs;         // row stride 64 u32
    const unsigned nm1 = (unsigned)(n2 - 1);
    const unsigned zrow = (unsigned)n2;      // all-zero pad row
    const int ffl = flags[1];
    const float bias0 = ldext(bias, ffl, 2 * lane);
    const float bias1 = ldext(bias, ffl, 2 * lane + 1);

    int curOff = off[w];                     // uniform-address broadcast loads
    int curDeg = deg[w];

    while (w < n2) {
        const int wn = w + nwaves;
        int nOff = 0, nDeg = 0;
        if (wn < n2) { nOff = off[wn]; nDeg = deg[wn]; }  // prefetch next node

        u32 pself = hsu[(size_t)w * 64 + lane];  // self-loop term (issued early)
        float ax = lo2f(pself), ay = hi2f(pself);
        int i = __builtin_amdgcn_readfirstlane(curOff);   // 4-aligned
        int end = i + __builtin_amdgcn_readfirstlane(curDeg);

        float bx = 0.f, by = 0.f, cx = 0.f, cy = 0.f, dx = 0.f, dy = 0.f;

        for (; i + 16 <= end; i += 16) {
            int4 qa = *(const int4*)(ssrc + i);
            int4 qb = *(const int4*)(ssrc + i + 4);
            int4 qc = *(const int4*)(ssrc + i + 8);
            int4 qd = *(const int4*)(ssrc + i + 12);
            unsigned s0 = (unsigned)qa.x; if (s0 > nm1) s0 = zrow;
            unsigned s1 = (unsigned)qa.y; if (s1 > nm1) s1 = zrow;
            unsigned s2 = (unsigned)qa.z; if (s2 > nm1) s2 = zrow;
            unsigned s3 = (unsigned)qa.w; if (s3 > nm1) s3 = zrow;
            unsigned s4 = (unsigned)qb.x; if (s4 > nm1) s4 = zrow;
            unsigned s5 = (unsigned)qb.y; if (s5 > nm1) s5 = zrow;
            unsigned s6 = (unsigned)qb.z; if (s6 > nm1) s6 = zrow;
            unsigned s7 = (unsigned)qb.w; if (s7 > nm1) s7 = zrow;
            unsigned s8 = (unsigned)qc.x; if (s8 > nm1) s8 = zrow;
            unsigned s9 = (unsigned)qc.y; if (s9 > nm1) s9 = zrow;
            unsigned sa = (unsigned)qc.z; if (sa > nm1) sa = zrow;
            unsigned sb = (unsigned)qc.w; if (sb > nm1) sb = zrow;
            unsigned sc = (unsigned)qd.x; if (sc > nm1) sc = zrow;
            unsigned sd = (unsigned)qd.y; if (sd > nm1) sd = zrow;
            unsigned se = (unsigned)qd.z; if (se > nm1) se = zrow;
            unsigned sf = (unsigned)qd.w; if (sf > nm1) sf = zrow;
            u32 v0 = hsu[(size_t)s0 * 64 + lane];
            u32 v1 = hsu[(size_t)s1 * 64 + lane];
            u32 v2 = hsu[(size_t)s2 * 64 + lane];
            u32 v3 = hsu[(size_t)s3 * 64 + lane];
            u32 v4 = hsu[(size_t)s4 * 64 + lane];
            u32 v5 = hsu[(size_t)s5 * 64 + lane];
            u32 v6 = hsu[(size_t)s6 * 64 + lane];
            u32 v7 = hsu[(size_t)s7 * 64 + lane];
            u32 v8 = hsu[(size_t)s8 * 64 + lane];
            u32 v9 = hsu[(size_t)s9 * 64 + lane];
            u32 va = hsu[(size_t)sa * 64 + lane];
            u32 vb = hsu[(size_t)sb * 64 + lane];
            u32 vc = hsu[(size_t)sc * 64 + lane];
            u32 vd = hsu[(size_t)sd * 64 + lane];
            u32 ve = hsu[(size_t)se * 64 + lane];
            u32 vf = hsu[(size_t)sf * 64 + lane];
            ax += lo2f(v0); ay += hi2f(v0);
            bx += lo2f(v1); by += hi2f(v1);
            cx += lo2f(v2); cy += hi2f(v2);
            dx += lo2f(v3); dy += hi2f(v3);
            ax += lo2f(v4); ay += hi2f(v4);
            bx += lo2f(v5); by += hi2f(v5);
            cx += lo2f(v6); cy += hi2f(v6);
            dx += lo2f(v7); dy += hi2f(v7);
            ax += lo2f(v8); ay += hi2f(v8);
            bx += lo2f(v9); by += hi2f(v9);
            cx += lo2f(va); cy += hi2f(va);
            dx += lo2f(vb); dy += hi2f(vb);
            ax += lo2f(vc); ay += hi2f(vc);
            bx += lo2f(vd); by += hi2f(vd);
            cx += lo2f(ve); cy += hi2f(ve);
            dx += lo2f(vf); dy += hi2f(vf);
        }
        for (; i < end; i += 4) {   // tail quads (start stays 4-aligned)
            int4 qa = *(const int4*)(ssrc + i);   // may include pad slots
            unsigned s0 = (unsigned)qa.x; if (s0 > nm1) s0 = zrow;
            unsigned s1 = (unsigned)qa.y; if (i + 1 >= end || s1 > nm1) s1 = zrow;
            unsigned s2 = (unsigned)qa.z; if (i + 2 >= end || s2 > nm1) s2 = zrow;
            unsigned s3 = (unsigned)qa.w; if (i + 3 >= end || s3 > nm1) s3 = zrow;
            u32 v0 = hsu[(size_t)s0 * 64 + lane];
            u32 v1 = hsu[(size_t)s1 * 64 + lane];
            u32 v2 = hsu[(size_t)s2 * 64 + lane];
            u32 v3 = hsu[(size_t)s3 * 64 + lane];
            ax += lo2f(v0); ay += hi2f(v0);
            bx += lo2f(v1); by += hi2f(v1);
            cx += lo2f(v2); cy += hi2f(v2);
            dx += lo2f(v3); dy += hi2f(v3);
        }
        ax += bx + cx + dx;
        ay += by + cy + dy;

        float dv = dinv[w];
        float o0 = dv * ax + bias0;
        float o1 = dv * ay + bias1;
        if (relu) {
            o0 = fmaxf(o0, 0.f);
            o1 = fmaxf(o1, 0.f);
        }
        if (outf) ((float2*)outf)[(size_t)w * 64 + lane] = make_float2(o0, o1);
        else ((u32*)outb)[(size_t)w * 64 + lane] = (u32)f2bs(o0) | ((u32)f2bs(o1) << 16);

        if (imp && w >= half) {   // fused importance on final-timestep rows
            float cb = o0 * ldext(Wc, ffl, 2 * lane) + o1 * ldext(Wc, ffl, 2 * lane + 1);
            cb += __shfl_xor(cb, 32);
            cb += __shfl_xor(cb, 16);
            cb += __shfl_xor(cb, 8);
            cb += __shfl_xor(cb, 4);
            cb += __shfl_xor(cb, 2);
            cb += __shfl_xor(cb, 1);
            if (lane == 0) imp[w - half] = cb + ldext(bc, ffl, 0);
        }

        w = wn;
        curOff = nOff;
        curDeg = nDeg;
    }
}

// ---------------------------------------------------------------------------
extern "C" void kernel_launch(void* const* d_in, const int* in_sizes, int n_in,
                              void* d_out, int out_size, void* d_ws, size_t ws_size,
                              hipStream_t stream) {
    const int T = 2, C = 128;
    const int N = in_sizes[0] / (T * C);   // 50000
    const int S = in_sizes[1];             // edge buffer reported element count
    const int Emax = S / 4;                // upper bound on edges per timestep
    const int N2 = 2 * N;                  // global node space (both timesteps)

    const void* x_seq = d_in[0];
    const int* edges = (const int*)d_in[1];
    const void* W1 = d_in[2];
    const void* b1 = d_in[3];
    const void* W2 = d_in[4];
    const void* b2 = d_in[5];
    const void* Wc = d_in[6];
    const void* bc = d_in[7];

    // d_out is FLOAT32 (reference output dtype): [imp N][h_t0 N*C][h_t1 N*C]
    // R0||R1 is contiguous and g-indexed: row g of the fused layer-2 output.
    float* out = (float*)d_out;
    float* R = out + N;

    // workspace (~78 MB of 256 MB); pairs aliases hsb+hmb (contiguous, dead
    // during CSR build — first GEMM write happens after scat in stream order)
    char* p = (char*)d_ws;
    auto alloc = [&](size_t bytes) {
        char* r = p;
        p += (bytes + 255) & ~(size_t)255;
        return r;
    };
    int* flags = (int*)alloc(256);
    int* deg = (int*)alloc((size_t)N2 * 4);
    int* off = (int*)alloc((size_t)N2 * 4);
    float* dinv = (float*)alloc((size_t)N2 * 4);
    int* bkcnt = (int*)alloc(512 * 4);

    // dst-range bucketing over 2N nodes: <=512 buckets, <=1024 LDS cursors
    int shift = 8;
    while ((((N2 + (1 << shift) - 1) >> shift) > 512) && shift < 10) ++shift;
    const int NBUK = (N2 + (1 << shift) - 1) >> shift;
    // fixed per-bucket pair capacity, sized to the hsb+hmb alias region
    // (~4x the expected per-bucket load); multiple of 4 so bucket bases stay
    // 4-aligned for the int4 edge-index loads
    const size_t aliasBytes = (size_t)2 * N2 * C * 2;
    const int capP = (int)(aliasBytes / (8 * (size_t)NBUK)) & ~3;

    int* ssrc = (int*)alloc(((size_t)NBUK * capP + 256) * 4);  // sparse CSR (+slack)
    u16* W1t = (u16*)alloc(128 * 128 * 2);
    u16* W2t = (u16*)alloc(128 * 128 * 2);
    u16* hsb = (u16*)alloc((size_t)(N2 + 2) * C * 2);  // +pad zero row at idx N2
    u16* hmb = (u16*)alloc((size_t)N2 * C * 2);        // bf16 layer-1 activation
    u64* pairs = (u64*)hsb;                            // spans hsb+hmb (contiguous)

    const int gP = (2 * Emax + PCHUNK - 1) / PCHUNK;
    const int gW = (2 * 128 * 128 + 255) / 256;        // prep_w tail blocks
    const int gGA = 2048;                   // persistent gather: 8192 waves
    const int nwaves = gGA * 4;
    const int gG2 = (N2 + 63) / 64;         // mfma gemm: block per 64 rows

    detect_kernel<<<1, 64, 0, stream>>>(edges, (const u32*)x_seq, flags, bkcnt, S, N);

    // --- CSR build (both timesteps) + weight prep in one dispatch ---
    part_kernel<<<gP + gW, 256, 0, stream>>>(edges, flags, bkcnt, pairs, N, shift,
                                             capP, gP, W1, W2, W1t, W2t);
    scat_kernel<<<NBUK, 256, 0, stream>>>(pairs, bkcnt, deg, off, dinv,
                                          ssrc, N2, shift, capP);

    // --- layer 1 over all 2N rows: hsb = dinv*(X @ W1); hmb = relu(gather)+b1 ---
    gemm_mfma<<<gG2, 256, 0, stream>>>(x_seq, 1, W1t, flags, dinv, hsb, N2);
    gather_kernel<<<gGA, 256, 0, stream>>>(hsb, off, deg, ssrc, dinv, b1, flags,
                                           (float*)nullptr, hmb,
                                           nullptr, nullptr, (float*)nullptr,
                                           N2, N, 1, nwaves);

    // --- layer 2 over all 2N rows: hsb = dinv*(hmb @ W2); R = gather + b2 ---
    gemm_mfma<<<gG2, 256, 0, stream>>>(hmb, 0, W2t, flags, dinv, hsb, N2);
    gather_kernel<<<gGA, 256, 0, stream>>>(hsb, off, deg, ssrc, dinv, b2, flags,
                                           R, (u16*)nullptr,
                                           Wc, bc, out,
                                           N2, N, 0, nwaves);
}

// Round 9
// 298.501 us; speedup vs baseline: 1.0957x; 1.0957x over previous
//
#include <hip/hip_runtime.h>
#include <hip/hip_bf16.h>

typedef unsigned int u32;
typedef unsigned short u16;
typedef unsigned long long u64;
typedef __bf16 bf16x8 __attribute__((ext_vector_type(8)));
typedef short short8 __attribute__((ext_vector_type(8)));
typedef float floatx4 __attribute__((ext_vector_type(4)));

__device__ inline float b2f(u16 b) { return __uint_as_float((u32)b << 16); }
__device__ inline float lo2f(u32 p) { return __uint_as_float(p << 16); }
__device__ inline float hi2f(u32 p) { return __uint_as_float(p & 0xffff0000u); }
__device__ inline u16 f2bs(float f) {   // RNE f32 -> bf16 bits
    __hip_bfloat16 h = __float2bfloat16(f);
    return *reinterpret_cast<u16*>(&h);
}
// element i of an external float array: f32 (fl=1) or packed bf16 (fl=0)
__device__ inline float ldext(const void* p, int fl, int i) {
    return fl ? ((const float*)p)[i] : b2f(((const u16*)p)[i]);
}

// ---------------------------------------------------------------------------
// flags[0]: edge stride (1 = int64 layout, 0 = int32)
// flags[1]: float inputs are f32 (1) or packed bf16 (0)
// flags[2]: E (edges per timestep), decided by probing data extent
// Also clears bkcnt[512] (folded memset: saves one dispatch).
__global__ __launch_bounds__(64) void detect_kernel(const int* __restrict__ eb,
                                                    const u32* __restrict__ xw,
                                                    int* __restrict__ flags,
                                                    int* __restrict__ bkcnt,
                                                    int S, int n) {
    __shared__ int sh[64 * 3];
    int lane = threadIdx.x & 63;
    for (int j = lane; j < 512; j += 64) bkcnt[j] = 0;
    int zc = 0, explo = 0;
#pragma unroll
    for (int r = 0; r < 4; ++r) {
        int i = 64 * r + lane;
        zc += (eb[2 * i + 1] == 0) ? 1 : 0;   // int64: odd dwords are hi-words = 0
        u32 w = xw[i];
        int e = (int)((w >> 7) & 0xFF);       // exponent field of LOW half as bf16
        explo += (e >= 96 && e <= 140) ? 1 : 0;
    }
    sh[lane] = zc;
    sh[64 + lane] = explo;
    __syncthreads();
    int fl = 0;
    {
        int z = 0;
        for (int j = 0; j < 64; ++j) z += sh[j];
        fl = (z > 200) ? 1 : 0;   // wave-uniform
    }
    // probe logical indices [S/2, S/2+256): valid node ids => S counts logical
    // elements (E = S/4); garbage => S counts int32 words (E = S/8).
    int vc = 0;
#pragma unroll
    for (int r = 0; r < 4; ++r) {
        int li = S / 2 + 64 * r + lane;
        int v = fl ? eb[2 * li] : eb[li];
        vc += ((unsigned)v < (unsigned)n) ? 1 : 0;
    }
    sh[128 + lane] = vc;
    __syncthreads();
    if (lane == 0) {
        int vtot = 0, etot = 0;
        for (int j = 0; j < 64; ++j) vtot += sh[128 + j];
        for (int j = 0; j < 64; ++j) etot += sh[64 + j];
        flags[0] = fl;
        flags[1] = (etot >= 192) ? 0 : 1;   // bf16-packed signature else f32
        flags[2] = (vtot >= 240) ? (S / 4) : (S / 8);
    }
}

__device__ inline int load_edge(const int* eb, int fl, int idx) {
    return eb[fl ? (idx << 1) : idx];
}

// ---------------------------------------------------------------------------
// CSR build pass 1 (both timesteps): partition edges into global-dst-range
// buckets at FIXED capacity capP (region b*capP, no scan needed). Per-block
// LDS histogram -> one global atomicAdd per bucket -> (g_dst, g_src) u64
// pairs in ~150 B contiguous runs (near-full cache lines). Src stored as
// GLOBAL id t*N+src. Blocks >= gP instead transpose W1,W2 -> bf16 W1t,W2t
// (folded prep_w: saves one dispatch).
#define PCHUNK 4096
__global__ __launch_bounds__(256) void part_kernel(const int* __restrict__ eb,
                                                   const int* __restrict__ flags,
                                                   int* __restrict__ bkcnt,
                                                   u64* __restrict__ pairs,
                                                   int n, int shift, int capP,
                                                   int gP,
                                                   const void* __restrict__ W1,
                                                   const void* __restrict__ W2,
                                                   u16* __restrict__ W1t,
                                                   u16* __restrict__ W2t) {
    __shared__ int cnt[512];
    __shared__ int gbase[512];
    if ((int)blockIdx.x >= gP) {             // prep_w tail blocks
        int tid = (blockIdx.x - gP) * 256 + threadIdx.x;
        if (tid < 2 * 128 * 128) {
            int which = tid >> 14;
            int r = tid & 16383;
            const void* W = which ? W2 : W1;
            u16* Wt = which ? W2t : W1t;
            int c = r >> 7, k = r & 127;
            Wt[c * 128 + k] = f2bs(ldext(W, flags[1], k * 128 + c));
        }
        return;
    }
    const int E = flags[2];
    const int fl = flags[0];
    const int nbuk = (2 * n + (1 << shift) - 1) >> shift;
    const int tid = threadIdx.x;
    for (int i = tid; i < nbuk; i += 256) cnt[i] = 0;
    __syncthreads();
    const int e0 = blockIdx.x * PCHUNK;
    u32 sv[16]; int gv[16], rk[16];
#pragma unroll
    for (int j = 0; j < 16; ++j) {
        int e = e0 + j * 256 + tid;
        u32 gs = 0; int g = -1;
        if (e < 2 * E) {
            int t = (e >= E) ? 1 : 0;
            int le = e - t * E;
            gs = (u32)(t * n) + (u32)load_edge(eb, fl, t * 2 * E + le);
            unsigned du = (unsigned)load_edge(eb, fl, t * 2 * E + E + le);
            if (du < (unsigned)n) g = t * n + (int)du;
        }
        sv[j] = gs;
        gv[j] = g;
        rk[j] = (g >= 0) ? atomicAdd(&cnt[g >> shift], 1) : 0;   // rank in bucket
    }
    __syncthreads();
    for (int b = tid; b < nbuk; b += 256) {
        int c = cnt[b];
        gbase[b] = c ? atomicAdd(&bkcnt[b], c) : 0;              // reserve run
    }
    __syncthreads();
#pragma unroll
    for (int j = 0; j < 16; ++j) {
        if (gv[j] >= 0) {
            int b = gv[j] >> shift;
            int idx = gbase[b] + rk[j];
            if (idx < capP)                                      // overflow guard
                pairs[(size_t)b * capP + idx] =
                    ((u64)(u32)gv[j] << 32) | sv[j];
        }
    }
}

// ---------------------------------------------------------------------------
// CSR build pass 2: one block per bucket. LDS histogram of the bucket's pairs
// gives local degrees; LDS exclusive scan over 4-ALIGNED (padded) degrees
// gives each node a 4-aligned start in the sparse ssrc layout (enables int4
// edge-index loads in the gather; pad slots are never consumed because the
// gather clamps e>=end elements to the zero row). deg/off/dinv coalesced;
// then in-bucket ssrc scatter (~16 KB window, L2-hot, full-line writebacks).
__global__ __launch_bounds__(256) void scat_kernel(const u64* __restrict__ pairs,
                                                   const int* __restrict__ bkcnt,
                                                   int* __restrict__ deg,
                                                   int* __restrict__ off,
                                                   float* __restrict__ dinv,
                                                   int* __restrict__ ssrc,
                                                   int n2, int shift, int capP) {
    __shared__ int hist[1024];   // histogram, then reused as scatter cursors
    __shared__ int lscan[256];
    const int b = blockIdx.x;
    const int d0 = b << shift;
    if (d0 >= n2) return;
    int nn = (1 << shift);
    if (d0 + nn > n2) nn = n2 - d0;
    const int tid = threadIdx.x;
    for (int j = tid; j < nn; j += 256) hist[j] = 0;
    __syncthreads();
    int cnt = bkcnt[b];
    if (cnt > capP) cnt = capP;
    const int gb = b * capP;                 // fixed sparse base (4-aligned)
    const u64* pb = pairs + (size_t)gb;
    for (int i = tid; i < cnt; i += 256) {
        unsigned dl = (unsigned)(int)(pb[i] >> 32) - (unsigned)d0;
        if (dl < (unsigned)nn) atomicAdd(&hist[dl], 1);
    }
    __syncthreads();
    // exclusive scan of PADDED degrees: thread t owns elements [4t, 4t+4)
    int base4 = tid * 4;
    int s0 = 0, s1 = 0, s2 = 0, s3 = 0;
    if (base4 < nn) {
        s0 = hist[base4];
        s1 = (base4 + 1 < nn) ? hist[base4 + 1] : 0;
        s2 = (base4 + 2 < nn) ? hist[base4 + 2] : 0;
        s3 = (base4 + 3 < nn) ? hist[base4 + 3] : 0;
    }
    int p0 = (s0 + 3) & ~3, p1 = (s1 + 3) & ~3;
    int p2 = (s2 + 3) & ~3, p3 = (s3 + 3) & ~3;
    int tsum = p0 + p1 + p2 + p3;
    lscan[tid] = tsum;
    __syncthreads();
    int val = tsum;
    for (int o = 1; o < 256; o <<= 1) {
        int add = (tid >= o) ? lscan[tid - o] : 0;
        __syncthreads();
        val += add;
        lscan[tid] = val;
        __syncthreads();
    }
    int texcl = val - tsum;                  // exclusive prefix (padded)
    if (base4 < nn) {
        int g = d0 + base4;
        int o0 = gb + texcl;
        deg[g] = s0; off[g] = o0; dinv[g] = rsqrtf((float)(s0 + 1));
        hist[base4] = o0;
        if (base4 + 1 < nn) {
            int o1 = o0 + p0;
            deg[g + 1] = s1; off[g + 1] = o1; dinv[g + 1] = rsqrtf((float)(s1 + 1));
            hist[base4 + 1] = o1;
        }
        if (base4 + 2 < nn) {
            int o2 = o0 + p0 + p1;
            deg[g + 2] = s2; off[g + 2] = o2; dinv[g + 2] = rsqrtf((float)(s2 + 1));
            hist[base4 + 2] = o2;
        }
        if (base4 + 3 < nn) {
            int o3 = o0 + p0 + p1 + p2;
            deg[g + 3] = s3; off[g + 3] = o3; dinv[g + 3] = rsqrtf((float)(s3 + 1));
            hist[base4 + 3] = o3;
        }
    }
    __syncthreads();
    const int limit = gb + capP;
    for (int i = tid; i < cnt; i += 256) {
        u64 p = pb[i];
        unsigned dl = (unsigned)(int)(p >> 32) - (unsigned)d0;
        if (dl < (unsigned)nn) {
            int pos = atomicAdd(&hist[dl], 1);
            if (pos < limit) ssrc[pos] = (int)(u32)p;
        }
    }
}

// ---------------------------------------------------------------------------
// MFMA GEMM over the unified 2N-row space: hs[g][c] = bf16( dinv[g] * X[g].W )
// mfma_f32_16x16x32_bf16. Block = 4 waves, 64 rows/block; wave = 16 rows x
// 128 cols = 8 col-tiles x 4 K-steps = 32 MFMAs. Wt staged in LDS, row
// stride 136 bf16 (2-way bank aliasing only -> free). Block 0 also zeroes
// the gather pad row at index n (folded memset; runs after scat consumed
// the aliased pairs region, before any gather reads it).
// Verified layouts (learn_hip m89/m91): A[m=lane&15][k=quad*8+j],
// B[n=lane&15][k=quad*8+j], C/D col=lane&15, row=quad*4+reg.
__global__ __launch_bounds__(256) void gemm_mfma(const void* __restrict__ Xv,
                                                 int x_ext,
                                                 const u16* __restrict__ Wt,
                                                 const int* __restrict__ flags,
                                                 const float* __restrict__ dinv,
                                                 u16* __restrict__ hs, int n) {
    if (blockIdx.x == 0 && threadIdx.x < 64)
        ((u32*)hs)[(size_t)n * 64 + threadIdx.x] = 0;   // pad row
    __shared__ u16 Ws[128 * 136];  // Wt[c][k], padded stride 136
    {
        u32* wsu = (u32*)Ws;
        const u32* wtu = (const u32*)Wt;
        for (int i = threadIdx.x; i < 128 * 64; i += 256) {
            int c = i >> 6, kk = i & 63;
            wsu[c * 68 + kk] = wtu[i];
        }
    }
    __syncthreads();

    const int wave = threadIdx.x >> 6;
    const int lane = threadIdx.x & 63;
    const int m = lane & 15;
    const int quad = lane >> 4;
    const int node0 = blockIdx.x * 64 + wave * 16;
    if (node0 >= n) return;

    const int xf32 = x_ext ? flags[1] : 0;   // internal buffers are bf16
    int va = node0 + m;
    if (va > n - 1) va = n - 1;              // clamp; stores guarded

    floatx4 acc[8];
#pragma unroll
    for (int t = 0; t < 8; ++t) acc[t] = (floatx4){0.f, 0.f, 0.f, 0.f};

#pragma unroll
    for (int ks = 0; ks < 4; ++ks) {
        bf16x8 a;
        if (xf32) {
            const float* Xf = (const float*)Xv + (size_t)va * 128 + ks * 32 + quad * 8;
            float4 x0 = *(const float4*)Xf;
            float4 x1 = *(const float4*)(Xf + 4);
            short8 as;
            as[0] = (short)f2bs(x0.x); as[1] = (short)f2bs(x0.y);
            as[2] = (short)f2bs(x0.z); as[3] = (short)f2bs(x0.w);
            as[4] = (short)f2bs(x1.x); as[5] = (short)f2bs(x1.y);
            as[6] = (short)f2bs(x1.z); as[7] = (short)f2bs(x1.w);
            a = __builtin_bit_cast(bf16x8, as);
        } else {
            const u16* Xb = (const u16*)Xv + (size_t)va * 128 + ks * 32 + quad * 8;
            a = *(const bf16x8*)Xb;
        }
#pragma unroll
        for (int t = 0; t < 8; ++t) {
            const bf16x8 b = *(const bf16x8*)(Ws + (16 * t + m) * 136 + ks * 32 + quad * 8);
            acc[t] = __builtin_amdgcn_mfma_f32_16x16x32_bf16(a, b, acc[t], 0, 0, 0);
        }
    }

#pragma unroll
    for (int r = 0; r < 4; ++r) {
        int v = node0 + quad * 4 + r;
        if (v < n) {
            float dv = dinv[v];
#pragma unroll
            for (int t = 0; t < 8; ++t)
                hs[(size_t)v * 128 + 16 * t + m] = f2bs(acc[t][r] * dv);
        }
    }
}

// ---------------------------------------------------------------------------
// out[g] = act( dinv[g] * (hs[g] + sum_{u in in(g)} hs[u]) + bias ), g in [0,2N)
// DUAL-NODE waves: each wave owns nodes w0=2*gwave, w1=w0+1 and interleaves
// their latency chains (the gather is latency-bound: ~1.7% VMEM issue
// utilization at round-6's one-node-per-wave). 8 edges per node per iter;
// exhausted node clamps to the L1-hot zero pad row at n2 (free at this issue
// rate). Row loads keep the full-wave 256 B contiguous pattern (round-5
// lesson: multi-row dwordx4 address divergence is 2.7x slower). Deep grid
// (one block per 8 nodes) — round-7 lesson: persistent grids lose TLP.
// Lane owns column pair 2*lane. If imp != null, rows g >= half wave-reduce
// importance = final . Wc + bc.
__global__ __launch_bounds__(256) void gather_kernel(const u16* __restrict__ hs,
                                                     const int* __restrict__ off,
                                                     const int* __restrict__ deg,
                                                     const int* __restrict__ ssrc,
                                                     const float* __restrict__ dinv,
                                                     const void* __restrict__ bias,
                                                     const int* __restrict__ flags,
                                                     float* __restrict__ outf,
                                                     u16* __restrict__ outb,
                                                     const void* __restrict__ Wc,
                                                     const void* __restrict__ bc,
                                                     float* __restrict__ imp,
                                                     int n2, int half, int relu) {
    const int lane = threadIdx.x & 63;
    const int gw = (blockIdx.x * 256 + threadIdx.x) >> 6;   // global wave id
    const int w0 = 2 * gw;
    const int w1 = w0 + 1;
    if (w0 >= n2) return;
    const int hasB = (w1 < n2);

    const u32* hsu = (const u32*)hs;         // row stride 64 u32
    const unsigned nm1 = (unsigned)(n2 - 1);
    const unsigned zrow = (unsigned)n2;      // all-zero pad row

    int iA = __builtin_amdgcn_readfirstlane(off[w0]);       // 4-aligned
    int endA = iA + __builtin_amdgcn_readfirstlane(deg[w0]);
    int iB = 0, endB = 0;
    if (hasB) {
        iB = __builtin_amdgcn_readfirstlane(off[w1]);
        endB = iB + __builtin_amdgcn_readfirstlane(deg[w1]);
    }

    u32 pselfA = hsu[(size_t)w0 * 64 + lane];
    u32 pselfB = hasB ? hsu[(size_t)w1 * 64 + lane] : 0u;

    float a0x = lo2f(pselfA), a0y = hi2f(pselfA), a1x = 0.f, a1y = 0.f;
    float b0x = lo2f(pselfB), b0y = hi2f(pselfB), b1x = 0.f, b1y = 0.f;

    while (iA < endA || iB < endB) {
        unsigned sA0, sA1, sA2, sA3, sA4, sA5, sA6, sA7;
        unsigned sB0, sB1, sB2, sB3, sB4, sB5, sB6, sB7;
        if (iA < endA) {   // wave-uniform branch
            int4 qa = *(const int4*)(ssrc + iA);
            int4 qb = *(const int4*)(ssrc + iA + 4);
            sA0 = (iA + 0 < endA && (unsigned)qa.x <= nm1) ? (unsigned)qa.x : zrow;
            sA1 = (iA + 1 < endA && (unsigned)qa.y <= nm1) ? (unsigned)qa.y : zrow;
            sA2 = (iA + 2 < endA && (unsigned)qa.z <= nm1) ? (unsigned)qa.z : zrow;
            sA3 = (iA + 3 < endA && (unsigned)qa.w <= nm1) ? (unsigned)qa.w : zrow;
            sA4 = (iA + 4 < endA && (unsigned)qb.x <= nm1) ? (unsigned)qb.x : zrow;
            sA5 = (iA + 5 < endA && (unsigned)qb.y <= nm1) ? (unsigned)qb.y : zrow;
            sA6 = (iA + 6 < endA && (unsigned)qb.z <= nm1) ? (unsigned)qb.z : zrow;
            sA7 = (iA + 7 < endA && (unsigned)qb.w <= nm1) ? (unsigned)qb.w : zrow;
            iA += 8;
        } else {
            sA0 = sA1 = sA2 = sA3 = sA4 = sA5 = sA6 = sA7 = zrow;
        }
        if (iB < endB) {
            int4 qa = *(const int4*)(ssrc + iB);
            int4 qb = *(const int4*)(ssrc + iB + 4);
            sB0 = (iB + 0 < endB && (unsigned)qa.x <= nm1) ? (unsigned)qa.x : zrow;
            sB1 = (iB + 1 < endB && (unsigned)qa.y <= nm1) ? (unsigned)qa.y : zrow;
            sB2 = (iB + 2 < endB && (unsigned)qa.z <= nm1) ? (unsigned)qa.z : zrow;
            sB3 = (iB + 3 < endB && (unsigned)qa.w <= nm1) ? (unsigned)qa.w : zrow;
            sB4 = (iB + 4 < endB && (unsigned)qb.x <= nm1) ? (unsigned)qb.x : zrow;
            sB5 = (iB + 5 < endB && (unsigned)qb.y <= nm1) ? (unsigned)qb.y : zrow;
            sB6 = (iB + 6 < endB && (unsigned)qb.z <= nm1) ? (unsigned)qb.z : zrow;
            sB7 = (iB + 7 < endB && (unsigned)qb.w <= nm1) ? (unsigned)qb.w : zrow;
            iB += 8;
        } else {
            sB0 = sB1 = sB2 = sB3 = sB4 = sB5 = sB6 = sB7 = zrow;
        }
        u32 vA0 = hsu[(size_t)sA0 * 64 + lane];
        u32 vA1 = hsu[(size_t)sA1 * 64 + lane];
        u32 vA2 = hsu[(size_t)sA2 * 64 + lane];
        u32 vA3 = hsu[(size_t)sA3 * 64 + lane];
        u32 vB0 = hsu[(size_t)sB0 * 64 + lane];
        u32 vB1 = hsu[(size_t)sB1 * 64 + lane];
        u32 vB2 = hsu[(size_t)sB2 * 64 + lane];
        u32 vB3 = hsu[(size_t)sB3 * 64 + lane];
        u32 vA4 = hsu[(size_t)sA4 * 64 + lane];
        u32 vA5 = hsu[(size_t)sA5 * 64 + lane];
        u32 vA6 = hsu[(size_t)sA6 * 64 + lane];
        u32 vA7 = hsu[(size_t)sA7 * 64 + lane];
        u32 vB4 = hsu[(size_t)sB4 * 64 + lane];
        u32 vB5 = hsu[(size_t)sB5 * 64 + lane];
        u32 vB6 = hsu[(size_t)sB6 * 64 + lane];
        u32 vB7 = hsu[(size_t)sB7 * 64 + lane];
        a0x += lo2f(vA0); a0y += hi2f(vA0);
        a1x += lo2f(vA1); a1y += hi2f(vA1);
        a0x += lo2f(vA2); a0y += hi2f(vA2);
        a1x += lo2f(vA3); a1y += hi2f(vA3);
        a0x += lo2f(vA4); a0y += hi2f(vA4);
        a1x += lo2f(vA5); a1y += hi2f(vA5);
        a0x += lo2f(vA6); a0y += hi2f(vA6);
        a1x += lo2f(vA7); a1y += hi2f(vA7);
        b0x += lo2f(vB0); b0y += hi2f(vB0);
        b1x += lo2f(vB1); b1y += hi2f(vB1);
        b0x += lo2f(vB2); b0y += hi2f(vB2);
        b1x += lo2f(vB3); b1y += hi2f(vB3);
        b0x += lo2f(vB4); b0y += hi2f(vB4);
        b1x += lo2f(vB5); b1y += hi2f(vB5);
        b0x += lo2f(vB6); b0y += hi2f(vB6);
        b1x += lo2f(vB7); b1y += hi2f(vB7);
    }
    a0x += a1x; a0y += a1y;
    b0x += b1x; b0y += b1y;

    const int ffl = flags[1];
    const float bias0 = ldext(bias, ffl, 2 * lane);
    const float bias1 = ldext(bias, ffl, 2 * lane + 1);

    {   // node w0
        float dv = dinv[w0];
        float o0 = dv * a0x + bias0;
        float o1 = dv * a0y + bias1;
        if (relu) { o0 = fmaxf(o0, 0.f); o1 = fmaxf(o1, 0.f); }
        if (outf) ((float2*)outf)[(size_t)w0 * 64 + lane] = make_float2(o0, o1);
        else ((u32*)outb)[(size_t)w0 * 64 + lane] = (u32)f2bs(o0) | ((u32)f2bs(o1) << 16);
        if (imp && w0 >= half) {
            float cb = o0 * ldext(Wc, ffl, 2 * lane) + o1 * ldext(Wc, ffl, 2 * lane + 1);
            cb += __shfl_xor(cb, 32);
            cb += __shfl_xor(cb, 16);
            cb += __shfl_xor(cb, 8);
            cb += __shfl_xor(cb, 4);
            cb += __shfl_xor(cb, 2);
            cb += __shfl_xor(cb, 1);
            if (lane == 0) imp[w0 - half] = cb + ldext(bc, ffl, 0);
        }
    }
    if (hasB) {   // node w1
        float dv = dinv[w1];
        float o0 = dv * b0x + bias0;
        float o1 = dv * b0y + bias1;
        if (relu) { o0 = fmaxf(o0, 0.f); o1 = fmaxf(o1, 0.f); }
        if (outf) ((float2*)outf)[(size_t)w1 * 64 + lane] = make_float2(o0, o1);
        else ((u32*)outb)[(size_t)w1 * 64 + lane] = (u32)f2bs(o0) | ((u32)f2bs(o1) << 16);
        if (imp && w1 >= half) {
            float cb = o0 * ldext(Wc, ffl, 2 * lane) + o1 * ldext(Wc, ffl, 2 * lane + 1);
            cb += __shfl_xor(cb, 32);
            cb += __shfl_xor(cb, 16);
            cb += __shfl_xor(cb, 8);
            cb += __shfl_xor(cb, 4);
            cb += __shfl_xor(cb, 2);
            cb += __shfl_xor(cb, 1);
            if (lane == 0) imp[w1 - half] = cb + ldext(bc, ffl, 0);
        }
    }
}

// ---------------------------------------------------------------------------
extern "C" void kernel_launch(void* const* d_in, const int* in_sizes, int n_in,
                              void* d_out, int out_size, void* d_ws, size_t ws_size,
                              hipStream_t stream) {
    const int T = 2, C = 128;
    const int N = in_sizes[0] / (T * C);   // 50000
    const int S = in_sizes[1];             // edge buffer reported element count
    const int Emax = S / 4;                // upper bound on edges per timestep
    const int N2 = 2 * N;                  // global node space (both timesteps)

    const void* x_seq = d_in[0];
    const int* edges = (const int*)d_in[1];
    const void* W1 = d_in[2];
    const void* b1 = d_in[3];
    const void* W2 = d_in[4];
    const void* b2 = d_in[5];
    const void* Wc = d_in[6];
    const void* bc = d_in[7];

    // d_out is FLOAT32 (reference output dtype): [imp N][h_t0 N*C][h_t1 N*C]
    // R0||R1 is contiguous and g-indexed: row g of the fused layer-2 output.
    float* out = (float*)d_out;
    float* R = out + N;

    // workspace (~78 MB of 256 MB); pairs aliases hsb+hmb (contiguous, dead
    // during CSR build — first GEMM write happens after scat in stream order)
    char* p = (char*)d_ws;
    auto alloc = [&](size_t bytes) {
        char* r = p;
        p += (bytes + 255) & ~(size_t)255;
        return r;
    };
    int* flags = (int*)alloc(256);
    int* deg = (int*)alloc((size_t)N2 * 4);
    int* off = (int*)alloc((size_t)N2 * 4);
    float* dinv = (float*)alloc((size_t)N2 * 4);
    int* bkcnt = (int*)alloc(512 * 4);

    // dst-range bucketing over 2N nodes: <=512 buckets, <=1024 LDS cursors
    int shift = 8;
    while ((((N2 + (1 << shift) - 1) >> shift) > 512) && shift < 10) ++shift;
    const int NBUK = (N2 + (1 << shift) - 1) >> shift;
    // fixed per-bucket pair capacity, sized to the hsb+hmb alias region
    // (~4x the expected per-bucket load); multiple of 4 so bucket bases stay
    // 4-aligned for the int4 edge-index loads
    const size_t aliasBytes = (size_t)2 * N2 * C * 2;
    const int capP = (int)(aliasBytes / (8 * (size_t)NBUK)) & ~3;

    int* ssrc = (int*)alloc(((size_t)NBUK * capP + 256) * 4);  // sparse CSR (+slack)
    u16* W1t = (u16*)alloc(128 * 128 * 2);
    u16* W2t = (u16*)alloc(128 * 128 * 2);
    u16* hsb = (u16*)alloc((size_t)(N2 + 2) * C * 2);  // +pad zero row at idx N2
    u16* hmb = (u16*)alloc((size_t)N2 * C * 2);        // bf16 layer-1 activation
    u64* pairs = (u64*)hsb;                            // spans hsb+hmb (contiguous)

    const int gP = (2 * Emax + PCHUNK - 1) / PCHUNK;
    const int gW = (2 * 128 * 128 + 255) / 256;        // prep_w tail blocks
    const int gGA = (N2 + 7) / 8;           // dual-node gather: 8 nodes/block
    const int gG2 = (N2 + 63) / 64;         // mfma gemm: block per 64 rows

    detect_kernel<<<1, 64, 0, stream>>>(edges, (const u32*)x_seq, flags, bkcnt, S, N);

    // --- CSR build (both timesteps) + weight prep in one dispatch ---
    part_kernel<<<gP + gW, 256, 0, stream>>>(edges, flags, bkcnt, pairs, N, shift,
                                             capP, gP, W1, W2, W1t, W2t);
    scat_kernel<<<NBUK, 256, 0, stream>>>(pairs, bkcnt, deg, off, dinv,
                                          ssrc, N2, shift, capP);

    // --- layer 1 over all 2N rows: hsb = dinv*(X @ W1); hmb = relu(gather)+b1 ---
    gemm_mfma<<<gG2, 256, 0, stream>>>(x_seq, 1, W1t, flags, dinv, hsb, N2);
    gather_kernel<<<gGA, 256, 0, stream>>>(hsb, off, deg, ssrc, dinv, b1, flags,
                                           (float*)nullptr, hmb,
                                           nullptr, nullptr, (float*)nullptr,
                                           N2, N, 1);

    // --- layer 2 over all 2N rows: hsb = dinv*(hmb @ W2); R = gather + b2 ---
    gemm_mfma<<<gG2, 256, 0, stream>>>(hmb, 0, W2t, flags, dinv, hsb, N2);
    gather_kernel<<<gGA, 256, 0, stream>>>(hsb, off, deg, ssrc, dinv, b2, flags,
                                           R, (u16*)nullptr,
                                           Wc, bc, out,
                                           N2, N, 0);
}

// Round 10
// 284.374 us; speedup vs baseline: 1.1501x; 1.0497x over previous
//
#include <hip/hip_runtime.h>
#include <hip/hip_bf16.h>

typedef unsigned int u32;
typedef unsigned short u16;
typedef unsigned long long u64;
typedef __bf16 bf16x8 __attribute__((ext_vector_type(8)));
typedef short short8 __attribute__((ext_vector_type(8)));
typedef float floatx4 __attribute__((ext_vector_type(4)));

#define SENT 0x7FFFFFFF   // sentinel id: > any valid node -> clamps to zero row

__device__ inline float b2f(u16 b) { return __uint_as_float((u32)b << 16); }
__device__ inline float lo2f(u32 p) { return __uint_as_float(p << 16); }
__device__ inline float hi2f(u32 p) { return __uint_as_float(p & 0xffff0000u); }
__device__ inline u16 f2bs(float f) {   // RNE f32 -> bf16 bits
    __hip_bfloat16 h = __float2bfloat16(f);
    return *reinterpret_cast<u16*>(&h);
}
// element i of an external float array: f32 (fl=1) or packed bf16 (fl=0)
__device__ inline float ldext(const void* p, int fl, int i) {
    return fl ? ((const float*)p)[i] : b2f(((const u16*)p)[i]);
}

// ---------------------------------------------------------------------------
// flags[0]: edge stride (1 = int64 layout, 0 = int32)
// flags[1]: float inputs are f32 (1) or packed bf16 (0)
// flags[2]: E (edges per timestep), decided by probing data extent
// Also clears bkcnt[512] and the overflow cursor (folded memsets).
__global__ __launch_bounds__(64) void detect_kernel(const int* __restrict__ eb,
                                                    const u32* __restrict__ xw,
                                                    int* __restrict__ flags,
                                                    int* __restrict__ bkcnt,
                                                    int* __restrict__ ovfcur,
                                                    int S, int n) {
    __shared__ int sh[64 * 3];
    int lane = threadIdx.x & 63;
    for (int j = lane; j < 512; j += 64) bkcnt[j] = 0;
    if (lane == 0) *ovfcur = 0;
    int zc = 0, explo = 0;
#pragma unroll
    for (int r = 0; r < 4; ++r) {
        int i = 64 * r + lane;
        zc += (eb[2 * i + 1] == 0) ? 1 : 0;   // int64: odd dwords are hi-words = 0
        u32 w = xw[i];
        int e = (int)((w >> 7) & 0xFF);       // exponent field of LOW half as bf16
        explo += (e >= 96 && e <= 140) ? 1 : 0;
    }
    sh[lane] = zc;
    sh[64 + lane] = explo;
    __syncthreads();
    int fl = 0;
    {
        int z = 0;
        for (int j = 0; j < 64; ++j) z += sh[j];
        fl = (z > 200) ? 1 : 0;   // wave-uniform
    }
    // probe logical indices [S/2, S/2+256): valid node ids => S counts logical
    // elements (E = S/4); garbage => S counts int32 words (E = S/8).
    int vc = 0;
#pragma unroll
    for (int r = 0; r < 4; ++r) {
        int li = S / 2 + 64 * r + lane;
        int v = fl ? eb[2 * li] : eb[li];
        vc += ((unsigned)v < (unsigned)n) ? 1 : 0;
    }
    sh[128 + lane] = vc;
    __syncthreads();
    if (lane == 0) {
        int vtot = 0, etot = 0;
        for (int j = 0; j < 64; ++j) vtot += sh[128 + j];
        for (int j = 0; j < 64; ++j) etot += sh[64 + j];
        flags[0] = fl;
        flags[1] = (etot >= 192) ? 0 : 1;   // bf16-packed signature else f32
        flags[2] = (vtot >= 240) ? (S / 4) : (S / 8);
    }
}

__device__ inline int load_edge(const int* eb, int fl, int idx) {
    return eb[fl ? (idx << 1) : idx];
}

// ---------------------------------------------------------------------------
// CSR build pass 1 (both timesteps): partition edges into global-dst-range
// buckets at FIXED capacity capP (region b*capP, no scan needed). Per-block
// LDS histogram -> one global atomicAdd per bucket -> (g_dst, g_src) u64
// pairs in ~150 B contiguous runs (near-full cache lines). Src stored as
// GLOBAL id t*N+src. Blocks >= gP instead transpose W1,W2 -> bf16 W1t,W2t
// (folded prep_w: saves one dispatch).
#define PCHUNK 4096
__global__ __launch_bounds__(256) void part_kernel(const int* __restrict__ eb,
                                                   const int* __restrict__ flags,
                                                   int* __restrict__ bkcnt,
                                                   u64* __restrict__ pairs,
                                                   int n, int shift, int capP,
                                                   int gP,
                                                   const void* __restrict__ W1,
                                                   const void* __restrict__ W2,
                                                   u16* __restrict__ W1t,
                                                   u16* __restrict__ W2t) {
    __shared__ int cnt[512];
    __shared__ int gbase[512];
    if ((int)blockIdx.x >= gP) {             // prep_w tail blocks
        int tid = (blockIdx.x - gP) * 256 + threadIdx.x;
        if (tid < 2 * 128 * 128) {
            int which = tid >> 14;
            int r = tid & 16383;
            const void* W = which ? W2 : W1;
            u16* Wt = which ? W2t : W1t;
            int c = r >> 7, k = r & 127;
            Wt[c * 128 + k] = f2bs(ldext(W, flags[1], k * 128 + c));
        }
        return;
    }
    const int E = flags[2];
    const int fl = flags[0];
    const int nbuk = (2 * n + (1 << shift) - 1) >> shift;
    const int tid = threadIdx.x;
    for (int i = tid; i < nbuk; i += 256) cnt[i] = 0;
    __syncthreads();
    const int e0 = blockIdx.x * PCHUNK;
    u32 sv[16]; int gv[16], rk[16];
#pragma unroll
    for (int j = 0; j < 16; ++j) {
        int e = e0 + j * 256 + tid;
        u32 gs = 0; int g = -1;
        if (e < 2 * E) {
            int t = (e >= E) ? 1 : 0;
            int le = e - t * E;
            gs = (u32)(t * n) + (u32)load_edge(eb, fl, t * 2 * E + le);
            unsigned du = (unsigned)load_edge(eb, fl, t * 2 * E + E + le);
            if (du < (unsigned)n) g = t * n + (int)du;
        }
        sv[j] = gs;
        gv[j] = g;
        rk[j] = (g >= 0) ? atomicAdd(&cnt[g >> shift], 1) : 0;   // rank in bucket
    }
    __syncthreads();
    for (int b = tid; b < nbuk; b += 256) {
        int c = cnt[b];
        gbase[b] = c ? atomicAdd(&bkcnt[b], c) : 0;              // reserve run
    }
    __syncthreads();
#pragma unroll
    for (int j = 0; j < 16; ++j) {
        if (gv[j] >= 0) {
            int b = gv[j] >> shift;
            int idx = gbase[b] + rk[j];
            if (idx < capP)                                      // overflow guard
                pairs[(size_t)b * capP + idx] =
                    ((u64)(u32)gv[j] << 32) | sv[j];
        }
    }
}

// ---------------------------------------------------------------------------
// CSR build pass 2: one block per bucket. FIXED-32-SLOT layout: node g owns
// ssrc[g*32 .. g*32+32); pads sentinel-filled (SENT clamps to the zero row in
// the gather -> exact +0.0). Rare deg>32 spills to a compact overflow region
// (ovfoff[g] via global cursor). No prefix scan needed at all. LDS histogram
// gives degrees; deg/dinv coalesced; in-bucket scatter is L2-hot.
__global__ __launch_bounds__(256) void scat_kernel(const u64* __restrict__ pairs,
                                                   const int* __restrict__ bkcnt,
                                                   int* __restrict__ deg,
                                                   float* __restrict__ dinv,
                                                   int* __restrict__ ssrc,
                                                   int* __restrict__ ovf,
                                                   int* __restrict__ ovfoff,
                                                   int* __restrict__ ovfcur,
                                                   int n2, int shift, int capP) {
    __shared__ int hist[1024];
    __shared__ int cur[1024];
    const int b = blockIdx.x;
    const int d0 = b << shift;
    if (d0 >= n2) return;
    int nn = (1 << shift);
    if (d0 + nn > n2) nn = n2 - d0;
    const int tid = threadIdx.x;
    for (int j = tid; j < nn; j += 256) { hist[j] = 0; cur[j] = 0; }
    __syncthreads();
    int cnt = bkcnt[b];
    if (cnt > capP) cnt = capP;
    const u64* pb = pairs + (size_t)b * capP;
    for (int i = tid; i < cnt; i += 256) {
        unsigned dl = (unsigned)(int)(pb[i] >> 32) - (unsigned)d0;
        if (dl < (unsigned)nn) atomicAdd(&hist[dl], 1);
    }
    __syncthreads();
    // degrees -> deg/dinv/overflow alloc; sentinel-fill pad slots [deg,32)
    for (int j = tid; j < nn; j += 256) {
        int d = hist[j];
        int g = d0 + j;
        deg[g] = d;
        dinv[g] = rsqrtf((float)(d + 1));
        if (d > 32) ovfoff[g] = atomicAdd(ovfcur, d - 32);
    }
    for (int idx = tid; idx < nn * 32; idx += 256) {
        int node = idx >> 5, slot = idx & 31;
        if (slot >= hist[node]) ssrc[(size_t)(d0 + node) * 32 + slot] = SENT;
    }
    __syncthreads();   // ovfoff visible before scatter reads it
    for (int i = tid; i < cnt; i += 256) {
        u64 p = pb[i];
        unsigned dl = (unsigned)(int)(p >> 32) - (unsigned)d0;
        if (dl < (unsigned)nn) {
            int g = d0 + (int)dl;
            int slot = atomicAdd(&cur[dl], 1);
            if (slot < 32) ssrc[(size_t)g * 32 + slot] = (int)(u32)p;
            else ovf[ovfoff[g] + slot - 32] = (int)(u32)p;
        }
    }
}

// ---------------------------------------------------------------------------
// MFMA GEMM over the unified 2N-row space: hs[g][c] = bf16( dinv[g] * X[g].W )
// mfma_f32_16x16x32_bf16. Block = 4 waves, 64 rows/block; wave = 16 rows x
// 128 cols = 8 col-tiles x 4 K-steps = 32 MFMAs. Wt staged in LDS, row
// stride 136 bf16 (2-way bank aliasing only -> free). Block 0 also zeroes
// the gather pad row at index n (folded memset; runs after scat consumed
// the aliased pairs region, before any gather reads it).
// Verified layouts (learn_hip m89/m91): A[m=lane&15][k=quad*8+j],
// B[n=lane&15][k=quad*8+j], C/D col=lane&15, row=quad*4+reg.
__global__ __launch_bounds__(256) void gemm_mfma(const void* __restrict__ Xv,
                                                 int x_ext,
                                                 const u16* __restrict__ Wt,
                                                 const int* __restrict__ flags,
                                                 const float* __restrict__ dinv,
                                                 u16* __restrict__ hs, int n) {
    if (blockIdx.x == 0 && threadIdx.x < 64)
        ((u32*)hs)[(size_t)n * 64 + threadIdx.x] = 0;   // pad row
    __shared__ u16 Ws[128 * 136];  // Wt[c][k], padded stride 136
    {
        u32* wsu = (u32*)Ws;
        const u32* wtu = (const u32*)Wt;
        for (int i = threadIdx.x; i < 128 * 64; i += 256) {
            int c = i >> 6, kk = i & 63;
            wsu[c * 68 + kk] = wtu[i];
        }
    }
    __syncthreads();

    const int wave = threadIdx.x >> 6;
    const int lane = threadIdx.x & 63;
    const int m = lane & 15;
    const int quad = lane >> 4;
    const int node0 = blockIdx.x * 64 + wave * 16;
    if (node0 >= n) return;

    const int xf32 = x_ext ? flags[1] : 0;   // internal buffers are bf16
    int va = node0 + m;
    if (va > n - 1) va = n - 1;              // clamp; stores guarded

    floatx4 acc[8];
#pragma unroll
    for (int t = 0; t < 8; ++t) acc[t] = (floatx4){0.f, 0.f, 0.f, 0.f};

#pragma unroll
    for (int ks = 0; ks < 4; ++ks) {
        bf16x8 a;
        if (xf32) {
            const float* Xf = (const float*)Xv + (size_t)va * 128 + ks * 32 + quad * 8;
            float4 x0 = *(const float4*)Xf;
            float4 x1 = *(const float4*)(Xf + 4);
            short8 as;
            as[0] = (short)f2bs(x0.x); as[1] = (short)f2bs(x0.y);
            as[2] = (short)f2bs(x0.z); as[3] = (short)f2bs(x0.w);
            as[4] = (short)f2bs(x1.x); as[5] = (short)f2bs(x1.y);
            as[6] = (short)f2bs(x1.z); as[7] = (short)f2bs(x1.w);
            a = __builtin_bit_cast(bf16x8, as);
        } else {
            const u16* Xb = (const u16*)Xv + (size_t)va * 128 + ks * 32 + quad * 8;
            a = *(const bf16x8*)Xb;
        }
#pragma unroll
        for (int t = 0; t < 8; ++t) {
            const bf16x8 b = *(const bf16x8*)(Ws + (16 * t + m) * 136 + ks * 32 + quad * 8);
            acc[t] = __builtin_amdgcn_mfma_f32_16x16x32_bf16(a, b, acc[t], 0, 0, 0);
        }
    }

#pragma unroll
    for (int r = 0; r < 4; ++r) {
        int v = node0 + quad * 4 + r;
        if (v < n) {
            float dv = dinv[v];
#pragma unroll
            for (int t = 0; t < 8; ++t)
                hs[(size_t)v * 128 + 16 * t + m] = f2bs(acc[t][r] * dv);
        }
    }
}

// ---------------------------------------------------------------------------
// out[g] = act( dinv[g] * (hs[g] + sum_{u in in(g)} hs[u]) + bias ), g in [0,2N)
// FIXED-32 BATCH gather: node g's edges live at ssrc[g*32..g*32+32), sentinel
// pads clamp to the zero row (exact +0.0). One branchless batch per wave: 8
// int4 index loads from a fixed scalar base (no off[] chain, no loop, no
// positional checks — round-9 lesson: per-element bound checks double VALU),
// then 32 independent row loads in flight. Rare deg>32 overflow via compact
// side region (uniform branch). Row loads keep the full-wave 256 B contiguous
// pattern (round-5 lesson). Deep grid (round-7 lesson). Lane owns column pair
// 2*lane. If imp != null, rows g >= half wave-reduce importance.
__global__ __launch_bounds__(256) void gather_kernel(const u16* __restrict__ hs,
                                                     const int* __restrict__ deg,
                                                     const int* __restrict__ ssrc,
                                                     const int* __restrict__ ovf,
                                                     const int* __restrict__ ovfoff,
                                                     const float* __restrict__ dinv,
                                                     const void* __restrict__ bias,
                                                     const int* __restrict__ flags,
                                                     float* __restrict__ outf,
                                                     u16* __restrict__ outb,
                                                     const void* __restrict__ Wc,
                                                     const void* __restrict__ bc,
                                                     float* __restrict__ imp,
                                                     int n2, int half, int relu) {
    const int lane = threadIdx.x & 63;
    int w = __builtin_amdgcn_readfirstlane((blockIdx.x * 256 + threadIdx.x) >> 6);
    if (w >= n2) return;

    const u32* hsu = (const u32*)hs;         // row stride 64 u32
    const unsigned nm1 = (unsigned)(n2 - 1);
    const unsigned zrow = (unsigned)n2;      // all-zero pad row

    const int dg = __builtin_amdgcn_readfirstlane(deg[w]);
    const int* sp = ssrc + (size_t)w * 32;   // scalar base, fixed stride

    int4 q0 = *(const int4*)(sp);
    int4 q1 = *(const int4*)(sp + 4);
    int4 q2 = *(const int4*)(sp + 8);
    int4 q3 = *(const int4*)(sp + 12);
    int4 q4 = *(const int4*)(sp + 16);
    int4 q5 = *(const int4*)(sp + 20);
    int4 q6 = *(const int4*)(sp + 24);
    int4 q7 = *(const int4*)(sp + 28);
    u32 pself = hsu[(size_t)w * 64 + lane];  // self-loop term

#define CLAMP(x) ((unsigned)(x) > nm1 ? zrow : (unsigned)(x))
    unsigned s00 = CLAMP(q0.x), s01 = CLAMP(q0.y), s02 = CLAMP(q0.z), s03 = CLAMP(q0.w);
    unsigned s04 = CLAMP(q1.x), s05 = CLAMP(q1.y), s06 = CLAMP(q1.z), s07 = CLAMP(q1.w);
    unsigned s08 = CLAMP(q2.x), s09 = CLAMP(q2.y), s10 = CLAMP(q2.z), s11 = CLAMP(q2.w);
    unsigned s12 = CLAMP(q3.x), s13 = CLAMP(q3.y), s14 = CLAMP(q3.z), s15 = CLAMP(q3.w);
    unsigned s16 = CLAMP(q4.x), s17 = CLAMP(q4.y), s18 = CLAMP(q4.z), s19 = CLAMP(q4.w);
    unsigned s20 = CLAMP(q5.x), s21 = CLAMP(q5.y), s22 = CLAMP(q5.z), s23 = CLAMP(q5.w);
    unsigned s24 = CLAMP(q6.x), s25 = CLAMP(q6.y), s26 = CLAMP(q6.z), s27 = CLAMP(q6.w);
    unsigned s28 = CLAMP(q7.x), s29 = CLAMP(q7.y), s30 = CLAMP(q7.z), s31 = CLAMP(q7.w);
#undef CLAMP

    float ax = lo2f(pself), ay = hi2f(pself);
    float bx = 0.f, by = 0.f, cx = 0.f, cy = 0.f, dx = 0.f, dy = 0.f;

#define ROW(s) hsu[(size_t)(s) * 64 + lane]
    {   // group 0
        u32 v0 = ROW(s00), v1 = ROW(s01), v2 = ROW(s02), v3 = ROW(s03);
        u32 v4 = ROW(s04), v5 = ROW(s05), v6 = ROW(s06), v7 = ROW(s07);
        ax += lo2f(v0); ay += hi2f(v0);  bx += lo2f(v1); by += hi2f(v1);
        cx += lo2f(v2); cy += hi2f(v2);  dx += lo2f(v3); dy += hi2f(v3);
        ax += lo2f(v4); ay += hi2f(v4);  bx += lo2f(v5); by += hi2f(v5);
        cx += lo2f(v6); cy += hi2f(v6);  dx += lo2f(v7); dy += hi2f(v7);
    }
    {   // group 1
        u32 v0 = ROW(s08), v1 = ROW(s09), v2 = ROW(s10), v3 = ROW(s11);
        u32 v4 = ROW(s12), v5 = ROW(s13), v6 = ROW(s14), v7 = ROW(s15);
        ax += lo2f(v0); ay += hi2f(v0);  bx += lo2f(v1); by += hi2f(v1);
        cx += lo2f(v2); cy += hi2f(v2);  dx += lo2f(v3); dy += hi2f(v3);
        ax += lo2f(v4); ay += hi2f(v4);  bx += lo2f(v5); by += hi2f(v5);
        cx += lo2f(v6); cy += hi2f(v6);  dx += lo2f(v7); dy += hi2f(v7);
    }
    {   // group 2
        u32 v0 = ROW(s16), v1 = ROW(s17), v2 = ROW(s18), v3 = ROW(s19);
        u32 v4 = ROW(s20), v5 = ROW(s21), v6 = ROW(s22), v7 = ROW(s23);
        ax += lo2f(v0); ay += hi2f(v0);  bx += lo2f(v1); by += hi2f(v1);
        cx += lo2f(v2); cy += hi2f(v2);  dx += lo2f(v3); dy += hi2f(v3);
        ax += lo2f(v4); ay += hi2f(v4);  bx += lo2f(v5); by += hi2f(v5);
        cx += lo2f(v6); cy += hi2f(v6);  dx += lo2f(v7); dy += hi2f(v7);
    }
    {   // group 3
        u32 v0 = ROW(s24), v1 = ROW(s25), v2 = ROW(s26), v3 = ROW(s27);
        u32 v4 = ROW(s28), v5 = ROW(s29), v6 = ROW(s30), v7 = ROW(s31);
        ax += lo2f(v0); ay += hi2f(v0);  bx += lo2f(v1); by += hi2f(v1);
        cx += lo2f(v2); cy += hi2f(v2);  dx += lo2f(v3); dy += hi2f(v3);
        ax += lo2f(v4); ay += hi2f(v4);  bx += lo2f(v5); by += hi2f(v5);
        cx += lo2f(v6); cy += hi2f(v6);  dx += lo2f(v7); dy += hi2f(v7);
    }

    if (dg > 32) {   // rare overflow (P ~ 1e-4), wave-uniform branch
        int ob = __builtin_amdgcn_readfirstlane(ovfoff[w]);
        int cnt = dg - 32;
        for (int j = 0; j < cnt; ++j) {
            unsigned s = (unsigned)ovf[ob + j];
            if (s > nm1) s = zrow;
            u32 v = ROW(s);
            ax += lo2f(v); ay += hi2f(v);
        }
    }
#undef ROW

    ax += bx + cx + dx;
    ay += by + cy + dy;

    const int ffl = flags[1];
    const float dv = dinv[w];
    float o0 = dv * ax + ldext(bias, ffl, 2 * lane);
    float o1 = dv * ay + ldext(bias, ffl, 2 * lane + 1);
    if (relu) {
        o0 = fmaxf(o0, 0.f);
        o1 = fmaxf(o1, 0.f);
    }
    if (outf) ((float2*)outf)[(size_t)w * 64 + lane] = make_float2(o0, o1);
    else ((u32*)outb)[(size_t)w * 64 + lane] = (u32)f2bs(o0) | ((u32)f2bs(o1) << 16);

    if (imp && w >= half) {   // fused importance on final-timestep rows
        float cb = o0 * ldext(Wc, ffl, 2 * lane) + o1 * ldext(Wc, ffl, 2 * lane + 1);
        cb += __shfl_xor(cb, 32);
        cb += __shfl_xor(cb, 16);
        cb += __shfl_xor(cb, 8);
        cb += __shfl_xor(cb, 4);
        cb += __shfl_xor(cb, 2);
        cb += __shfl_xor(cb, 1);
        if (lane == 0) imp[w - half] = cb + ldext(bc, ffl, 0);
    }
}

// ---------------------------------------------------------------------------
extern "C" void kernel_launch(void* const* d_in, const int* in_sizes, int n_in,
                              void* d_out, int out_size, void* d_ws, size_t ws_size,
                              hipStream_t stream) {
    const int T = 2, C = 128;
    const int N = in_sizes[0] / (T * C);   // 50000
    const int S = in_sizes[1];             // edge buffer reported element count
    const int Emax = S / 4;                // upper bound on edges per timestep
    const int N2 = 2 * N;                  // global node space (both timesteps)

    const void* x_seq = d_in[0];
    const int* edges = (const int*)d_in[1];
    const void* W1 = d_in[2];
    const void* b1 = d_in[3];
    const void* W2 = d_in[4];
    const void* b2 = d_in[5];
    const void* Wc = d_in[6];
    const void* bc = d_in[7];

    // d_out is FLOAT32 (reference output dtype): [imp N][h_t0 N*C][h_t1 N*C]
    // R0||R1 is contiguous and g-indexed: row g of the fused layer-2 output.
    float* out = (float*)d_out;
    float* R = out + N;

    // workspace (~75 MB of 256 MB); pairs aliases hsb+hmb (contiguous, dead
    // during CSR build — first GEMM write happens after scat in stream order)
    char* p = (char*)d_ws;
    auto alloc = [&](size_t bytes) {
        char* r = p;
        p += (bytes + 255) & ~(size_t)255;
        return r;
    };
    int* flags = (int*)alloc(256);
    int* deg = (int*)alloc((size_t)N2 * 4);
    float* dinv = (float*)alloc((size_t)N2 * 4);
    int* bkcnt = (int*)alloc(512 * 4);
    int* ovfcur = (int*)alloc(256);
    int* ovfoff = (int*)alloc((size_t)N2 * 4);

    // dst-range bucketing over 2N nodes: <=512 buckets, <=1024 LDS cursors
    int shift = 8;
    while ((((N2 + (1 << shift) - 1) >> shift) > 512) && shift < 10) ++shift;
    const int NBUK = (N2 + (1 << shift) - 1) >> shift;
    // fixed per-bucket pair capacity, sized to the hsb+hmb alias region
    // (~4x the expected per-bucket load for uniform edges)
    const size_t aliasBytes = (size_t)2 * N2 * C * 2;
    const int capP = (int)(aliasBytes / (8 * (size_t)NBUK)) & ~3;

    int* ssrc = (int*)alloc((size_t)N2 * 32 * 4);      // fixed 32 slots/node
    int* ovf = (int*)alloc((size_t)2 * Emax * 4);      // deg>32 spill region
    u16* W1t = (u16*)alloc(128 * 128 * 2);
    u16* W2t = (u16*)alloc(128 * 128 * 2);
    u16* hsb = (u16*)alloc((size_t)(N2 + 2) * C * 2);  // +pad zero row at idx N2
    u16* hmb = (u16*)alloc((size_t)N2 * C * 2);        // bf16 layer-1 activation
    u64* pairs = (u64*)hsb;                            // spans hsb+hmb (contiguous)

    const int gP = (2 * Emax + PCHUNK - 1) / PCHUNK;
    const int gW = (2 * 128 * 128 + 255) / 256;        // prep_w tail blocks
    const int gGA = (N2 + 3) / 4;           // gather: 4 nodes/block (1/wave)
    const int gG2 = (N2 + 63) / 64;         // mfma gemm: block per 64 rows

    detect_kernel<<<1, 64, 0, stream>>>(edges, (const u32*)x_seq, flags, bkcnt,
                                        ovfcur, S, N);

    // --- CSR build (both timesteps) + weight prep in one dispatch ---
    part_kernel<<<gP + gW, 256, 0, stream>>>(edges, flags, bkcnt, pairs, N, shift,
                                             capP, gP, W1, W2, W1t, W2t);
    scat_kernel<<<NBUK, 256, 0, stream>>>(pairs, bkcnt, deg, dinv, ssrc,
                                          ovf, ovfoff, ovfcur, N2, shift, capP);

    // --- layer 1 over all 2N rows: hsb = dinv*(X @ W1); hmb = relu(gather)+b1 ---
    gemm_mfma<<<gG2, 256, 0, stream>>>(x_seq, 1, W1t, flags, dinv, hsb, N2);
    gather_kernel<<<gGA, 256, 0, stream>>>(hsb, deg, ssrc, ovf, ovfoff, dinv, b1,
                                           flags, (float*)nullptr, hmb,
                                           nullptr, nullptr, (float*)nullptr,
                                           N2, N, 1);

    // --- layer 2 over all 2N rows: hsb = dinv*(hmb @ W2); R = gather + b2 ---
    gemm_mfma<<<gG2, 256, 0, stream>>>(hmb, 0, W2t, flags, dinv, hsb, N2);
    gather_kernel<<<gGA, 256, 0, stream>>>(hsb, deg, ssrc, ovf, ovfoff, dinv, b2,
                                           flags, R, (u16*)nullptr,
                                           Wc, bc, out,
                                           N2, N, 0);
}